// Round 7
// baseline (184.594 us; speedup 1.0000x reference)
//
#include <hip/hip_runtime.h>

// ---------------------------------------------------------------------------
// HIDecoder fused: y=z@Wy^T+by ; lin_{m,v}=einsum(gamma,W{m,v})+b ; gaussian
// log-lik epilogue.  gamma never materialized:
//   Weff[n=t*8+j][k] = sum_y M_j[t][y]*Wy[t*32+y][k],  M_j = Wm(j<4)/Wv(j>=4)
//   beff[n]          = b_j[t,d] + sum_y by[t*32+y]*M_j[t][y]
//
// History: R3 weff pre-swizzle. R5/R6 occupancy+coalesce. R9 register
// prefetch (traffic minimal 124MB, main 52.5us). Session law: dur ~= 22us +
// bytes/3.65TB/s; fused phase-convoy pins BW at ~2.4TB/s (read bursts and
// write bursts never overlap at HBM).
// R10 (this round): SPLIT into homogeneous kernels.
//  k1 hidec_gemm: stage z -> MFMA -> store bf16 lin DIRECTLY from fragments
//     to a fragment-ordered global layout (no LDS transpose, 1 barrier).
//     Layout: ushort addr = (rq*512 + n)*4 + reg, rq=row>>2, reg=row&3.
//     Per wave-inst: 4x128B segments (full sectors). ~67MB traffic.
//  k2 hidec_post: pure streaming epilogue, no LDS/barriers, thread=(rq,t):
//     reads 4KB-contig lin, 1KB-contig bx, 256B miss; writes the 4 out
//     streams coalesced. Stream-class kernel -> expect >=5TB/s.
//  Fallback to R9 fused kernel if ws_size < 34MB.
// ---------------------------------------------------------------------------

#define Bsz   32768
#define Tsz   64
#define Dsz   4
#define Ysz   32
#define Zsz   256
#define Nsz   512
#define BTtot (Bsz * Tsz)
#define EPS_  1e-3f
#define LOG2PI_ 1.8378770664093453f

#define BM       32            // batch rows per GEMM block
#define NT       512           // threads per GEMM block (8 waves)
#define ASTRIDE  264           // ushorts per staged-z row
#define LSTRIDE  524           // ushorts per lin row (fused fallback)
#define LINP_OFF 524288        // byte offset of linp in workspace
#define LINP_BYTES ((size_t)Bsz * Nsz * 2)   // 33.5 MB

typedef __attribute__((ext_vector_type(4))) float  f32x4;
typedef __attribute__((ext_vector_type(8))) short  short8;
typedef __attribute__((ext_vector_type(2))) unsigned int uint2v;

static __device__ __forceinline__ unsigned short f2bf(float f) {
    unsigned int u = __float_as_uint(f);
    return (unsigned short)((u + 0x7fffu + ((u >> 16) & 1u)) >> 16);   // RNE
}
static __device__ __forceinline__ float bf2f(unsigned short h) {
    return __uint_as_float(((unsigned int)h) << 16);
}
// HW RNE pack: low16 = bf16(a), high16 = bf16(b)
static __device__ __forceinline__ unsigned int cvt_pk_bf16(float a, float b) {
    unsigned int r;
    asm("v_cvt_pk_bf16_f32 %0, %1, %2" : "=v"(r) : "v"(a), "v"(b));
    return r;
}

// ---------------------------------------------------------------------------
// Prep: 64 blocks (one per t) x 256 threads (one per k).
// Writes weff in B-fragment order:
//   addr(n,k) = (((tau*8+kk)*4+q)*16+c)*8 + j,  tau=n>>4, c=n&15,
//   kk=k>>5, q=(k>>3)&3, j=k&7
// ---------------------------------------------------------------------------
__global__ __launch_bounds__(256)
void hidec_prep(const float* __restrict__ Wy, const float* __restrict__ by,
                const float* __restrict__ Wm, const float* __restrict__ bm,
                const float* __restrict__ Wv, const float* __restrict__ bv,
                unsigned short* __restrict__ weff, float* __restrict__ beff) {
    __shared__ float Ml[8][Ysz];
    __shared__ float byl[Ysz];
    const int t   = blockIdx.x;          // 0..63
    const int tid = threadIdx.x;
    {
        int j = tid >> 5, y = tid & 31;
        const float* src = (j < 4) ? Wm : Wv;
        Ml[j][y] = src[(t * Dsz + (j & 3)) * Ysz + y];
    }
    if (tid < Ysz) byl[tid] = by[t * Ysz + tid];
    __syncthreads();

    const int k = tid;                   // 0..255
    const int kk = k >> 5, q = (k >> 3) & 3, je = k & 7;
    float wy[Ysz];
#pragma unroll
    for (int y = 0; y < Ysz; ++y)
        wy[y] = Wy[(size_t)(t * Ysz + y) * Zsz + k];
#pragma unroll
    for (int j = 0; j < 8; ++j) {
        float acc = 0.f;
#pragma unroll
        for (int y = 0; y < Ysz; ++y) acc = fmaf(Ml[j][y], wy[y], acc);
        int n   = t * 8 + j;
        int tau = n >> 4, c = n & 15;
        weff[((((tau * 8 + kk) * 4 + q) * 16 + c) * 8) + je] = f2bf(acc);
    }
    if (tid < 8) {
        int d = tid & 3;
        float s = ((tid < 4) ? bm : bv)[t * Dsz + d];
        for (int y = 0; y < Ysz; ++y) s = fmaf(byl[y], Ml[tid][y], s);
        beff[t * 8 + tid] = s;
    }
}

// ---------------------------------------------------------------------------
// k1: GEMM only. 1024 blocks x 512 threads. Wave w owns cols w*64..w*64+63.
// Stores lin (bf16, +bias) straight from fragments to fragment-ordered global.
// ---------------------------------------------------------------------------
__global__ __launch_bounds__(NT, 4)
void hidec_gemm(const float* __restrict__ z, const unsigned short* __restrict__ weff,
                const float* __restrict__ beff, unsigned short* __restrict__ linp) {
    __shared__ unsigned short a_lds[BM * ASTRIDE];       // 16896 B

    const int tid  = threadIdx.x;
    const long row0 = (long)blockIdx.x * BM;

    // ---- stage z (32 x 256 fp32) -> bf16 LDS ------------------------------
#pragma unroll
    for (int i = 0; i < 4; ++i) {
        int idx4 = tid + i * NT;         // 2048 float4-groups
        int r  = idx4 >> 6;
        int c4 = idx4 & 63;
        float4 v = *(const float4*)(z + (row0 + r) * Zsz + c4 * 4);
        uint2v pk;
        pk.x = cvt_pk_bf16(v.x, v.y);
        pk.y = cvt_pk_bf16(v.z, v.w);
        *(uint2v*)&a_lds[r * ASTRIDE + c4 * 4] = pk;
    }

    const int lane = tid & 63;
    const int w    = tid >> 6;           // wave 0..7
    const int c    = lane & 15;
    const int q    = lane >> 4;

    // bias prefetch (L2-resident, overlaps barrier)
    float bb[4];
#pragma unroll
    for (int ti = 0; ti < 4; ++ti) bb[ti] = beff[w * 64 + ti * 16 + c];

    __syncthreads();

    // ---- GEMM: 32 x 512 x K=256, bf16 MFMA 16x16x32 -----------------------
    f32x4 acc[8];                        // [ti*2 + h]
#pragma unroll
    for (int i = 0; i < 8; ++i) acc[i] = (f32x4){0.f, 0.f, 0.f, 0.f};

    const unsigned short* wp = weff + ((size_t)(w * 4) * 8) * 512 + lane * 8;

#pragma unroll
    for (int kk = 0; kk < 8; ++kk) {
        short8 b0 = *(const short8*)(wp + kk * 512 + 0 * 4096);
        short8 b1 = *(const short8*)(wp + kk * 512 + 1 * 4096);
        short8 b2 = *(const short8*)(wp + kk * 512 + 2 * 4096);
        short8 b3 = *(const short8*)(wp + kk * 512 + 3 * 4096);
        short8 a0 = *(const short8*)&a_lds[(0 * 16 + c) * ASTRIDE + kk * 32 + q * 8];
        short8 a1 = *(const short8*)&a_lds[(1 * 16 + c) * ASTRIDE + kk * 32 + q * 8];
        acc[0] = __builtin_amdgcn_mfma_f32_16x16x32_bf16(a0, b0, acc[0], 0, 0, 0);
        acc[1] = __builtin_amdgcn_mfma_f32_16x16x32_bf16(a1, b0, acc[1], 0, 0, 0);
        acc[2] = __builtin_amdgcn_mfma_f32_16x16x32_bf16(a0, b1, acc[2], 0, 0, 0);
        acc[3] = __builtin_amdgcn_mfma_f32_16x16x32_bf16(a1, b1, acc[3], 0, 0, 0);
        acc[4] = __builtin_amdgcn_mfma_f32_16x16x32_bf16(a0, b2, acc[4], 0, 0, 0);
        acc[5] = __builtin_amdgcn_mfma_f32_16x16x32_bf16(a1, b2, acc[5], 0, 0, 0);
        acc[6] = __builtin_amdgcn_mfma_f32_16x16x32_bf16(a0, b3, acc[6], 0, 0, 0);
        acc[7] = __builtin_amdgcn_mfma_f32_16x16x32_bf16(a1, b3, acc[7], 0, 0, 0);
    }

    // ---- store lin in fragment order: ushort (rq*512 + n)*4 + reg ---------
    // rq = blockIdx*8 + h*4 + q (row quad), n = w*64 + ti*16 + c, reg = row&3
#pragma unroll
    for (int h = 0; h < 2; ++h) {
#pragma unroll
        for (int ti = 0; ti < 4; ++ti) {
            const f32x4 a = acc[ti * 2 + h];
            uint2v pk;
            pk.x = cvt_pk_bf16(a[0] + bb[ti], a[1] + bb[ti]);
            pk.y = cvt_pk_bf16(a[2] + bb[ti], a[3] + bb[ti]);
            size_t unit = ((size_t)blockIdx.x * 8 + h * 4 + q) * 512
                        + (w * 64 + ti * 16 + c);
            *(uint2v*)(linp + unit * 4) = pk;
        }
    }
}

// ---------------------------------------------------------------------------
// k2: pure streaming epilogue. 2048 blocks x 256 threads.
// thread = (rq, t): rq = blockIdx*4 + tid>>6 (row quad), t = tid&63.
// ---------------------------------------------------------------------------
__global__ __launch_bounds__(256)
void hidec_post(const float* __restrict__ bx, const int* __restrict__ miss,
                const float* __restrict__ dmean, const float* __restrict__ dvarp,
                const unsigned short* __restrict__ linp, float* __restrict__ out) {
    const int tid = threadIdx.x;
    const int t   = tid & 63;
    const long rq = (long)blockIdx.x * 4 + (tid >> 6);   // 0..8191

    // ---- load lin 64B contiguous (4KB per wave) ---------------------------
    const unsigned short* lp = linp + rq * 2048 + t * 32;
    short8 u01 = *(const short8*)(lp +  0);   // cols j=0,1 (4 regs each)
    short8 u23 = *(const short8*)(lp +  8);   // cols j=2,3
    short8 u45 = *(const short8*)(lp + 16);   // cols j=4,5
    short8 u67 = *(const short8*)(lp + 24);   // cols j=6,7

    // ---- load bx/miss for the 4 rows --------------------------------------
    float4 xq[4];
    int    mq[4];
#pragma unroll
    for (int r = 0; r < 4; ++r) {
        long bt = (rq * 4 + r) * Tsz + t;
        xq[r] = *(const float4*)(bx + bt * 4);
        mq[r] = miss[bt];
    }

    // ---- per-t constants --------------------------------------------------
    float4 dv4 = *(const float4*)(dvarp + t * 4);
    float4 dm4 = *(const float4*)(dmean + t * 4);
    float dca[4] = {fmaxf(dv4.x, EPS_), fmaxf(dv4.y, EPS_),
                    fmaxf(dv4.z, EPS_), fmaxf(dv4.w, EPS_)};
    float sqa[4] = {sqrtf(dca[0]), sqrtf(dca[1]), sqrtf(dca[2]), sqrtf(dca[3])};
    float dma[4] = {dm4.x, dm4.y, dm4.z, dm4.w};
    float sldv = __logf(dca[0]) + __logf(dca[1]) + __logf(dca[2]) + __logf(dca[3]);

#pragma unroll
    for (int r = 0; r < 4; ++r) {
        long bt = (rq * 4 + r) * Tsz + t;

        float lm[4], lv[4];
        lm[0] = bf2f((unsigned short)u01[r]);
        lm[1] = bf2f((unsigned short)u01[4 + r]);
        lm[2] = bf2f((unsigned short)u23[r]);
        lm[3] = bf2f((unsigned short)u23[4 + r]);
        lv[0] = bf2f((unsigned short)u45[r]);
        lv[1] = bf2f((unsigned short)u45[4 + r]);
        lv[2] = bf2f((unsigned short)u67[r]);
        lv[3] = bf2f((unsigned short)u67[4 + r]);

        float mk = (float)mq[r];
        float xa[4] = {xq[r].x, xq[r].y, xq[r].z, xq[r].w};

        float mean_o[4], var_o[4];
        float s = sldv;
        float evp = 1.f;
#pragma unroll
        for (int d = 0; d < 4; ++d) {
            float mean = fmaf(sqa[d], lm[d], dma[d]);
            float v    = lv[d];
            float sp   = fmaxf(v, 0.f) + __logf(1.f + __expf(-fabsf(v)));
            float ev   = fminf(fmaxf(sp, EPS_), 1e20f);
            float var  = dca[d] * ev;
            float diff = xa[d] - mean;
            s = fmaf(diff * diff, __builtin_amdgcn_rcpf(var), s);
            evp *= ev;
            mean_o[d] = mean;
            var_o[d]  = var;
        }
        s += __logf(evp);
        float logp = -0.5f * (s + 4.f * LOG2PI_);

        float lx = logp * mk;
        out[bt]         = lx;              // log_p_x       (256B/wave)
        out[BTtot + bt] = logp - lx;       // log_p_x_missing

        *(float4*)(out + 2L * BTtot + bt * 4) =
            (float4){mean_o[0], mean_o[1], mean_o[2], mean_o[3]};
        *(float4*)(out + 6L * BTtot + bt * 4) =
            (float4){var_o[0], var_o[1], var_o[2], var_o[3]};
    }
}

// ---------------------------------------------------------------------------
// Fallback: R9 fused kernel (used when workspace is too small for linp).
// ---------------------------------------------------------------------------
__global__ __launch_bounds__(NT, 4)
void hidec_fused(const float* __restrict__ z, const float* __restrict__ bx,
                 const int* __restrict__ miss, const float* __restrict__ dmean,
                 const float* __restrict__ dvarp, const unsigned short* __restrict__ weff,
                 const float* __restrict__ beff, float* __restrict__ out) {
    __shared__ unsigned short buf[BM * LSTRIDE];         // 33536 B
    const int tid  = threadIdx.x;
    const long row0 = (long)blockIdx.x * BM;

    unsigned short* a_lds = buf;
#pragma unroll
    for (int i = 0; i < 4; ++i) {
        int idx4 = tid + i * NT;
        int r  = idx4 >> 6;
        int c4 = idx4 & 63;
        float4 v = *(const float4*)(z + (row0 + r) * Zsz + c4 * 4);
        uint2v pk;
        pk.x = cvt_pk_bf16(v.x, v.y);
        pk.y = cvt_pk_bf16(v.z, v.w);
        *(uint2v*)&a_lds[r * ASTRIDE + c4 * 4] = pk;
    }
    __syncthreads();

    const int lane = tid & 63;
    const int w    = tid >> 6;
    const int c    = lane & 15;
    const int q    = lane >> 4;

    f32x4 acc[8];
#pragma unroll
    for (int i = 0; i < 8; ++i) acc[i] = (f32x4){0.f, 0.f, 0.f, 0.f};

    const unsigned short* wp = weff + ((size_t)(w * 4) * 8) * 512 + lane * 8;
#pragma unroll
    for (int kk = 0; kk < 8; ++kk) {
        short8 b0 = *(const short8*)(wp + kk * 512 + 0 * 4096);
        short8 b1 = *(const short8*)(wp + kk * 512 + 1 * 4096);
        short8 b2 = *(const short8*)(wp + kk * 512 + 2 * 4096);
        short8 b3 = *(const short8*)(wp + kk * 512 + 3 * 4096);
        short8 a0 = *(const short8*)&a_lds[(0 * 16 + c) * ASTRIDE + kk * 32 + q * 8];
        short8 a1 = *(const short8*)&a_lds[(1 * 16 + c) * ASTRIDE + kk * 32 + q * 8];
        acc[0] = __builtin_amdgcn_mfma_f32_16x16x32_bf16(a0, b0, acc[0], 0, 0, 0);
        acc[1] = __builtin_amdgcn_mfma_f32_16x16x32_bf16(a1, b0, acc[1], 0, 0, 0);
        acc[2] = __builtin_amdgcn_mfma_f32_16x16x32_bf16(a0, b1, acc[2], 0, 0, 0);
        acc[3] = __builtin_amdgcn_mfma_f32_16x16x32_bf16(a1, b1, acc[3], 0, 0, 0);
        acc[4] = __builtin_amdgcn_mfma_f32_16x16x32_bf16(a0, b2, acc[4], 0, 0, 0);
        acc[5] = __builtin_amdgcn_mfma_f32_16x16x32_bf16(a1, b2, acc[5], 0, 0, 0);
        acc[6] = __builtin_amdgcn_mfma_f32_16x16x32_bf16(a0, b3, acc[6], 0, 0, 0);
        acc[7] = __builtin_amdgcn_mfma_f32_16x16x32_bf16(a1, b3, acc[7], 0, 0, 0);
    }

    const int t = lane;
    float4 dv4 = *(const float4*)(dvarp + t * 4);
    float4 dm4 = *(const float4*)(dmean + t * 4);
    float4 xp[4];
    int    mp[4];
#pragma unroll
    for (int pp = 0; pp < 4; ++pp) {
        long bt = (row0 + pp * 8 + w) * Tsz + t;
        xp[pp] = *(const float4*)(bx + bt * 4);
        mp[pp] = miss[bt];
    }
    float bb[4];
#pragma unroll
    for (int ti = 0; ti < 4; ++ti) bb[ti] = beff[w * 64 + ti * 16 + c];
#pragma unroll
    for (int pp = 0; pp < 4; ++pp) {
        asm volatile("" : "+v"(xp[pp].x), "+v"(xp[pp].y),
                          "+v"(xp[pp].z), "+v"(xp[pp].w), "+v"(mp[pp]));
    }
    asm volatile("" : "+v"(dv4.x), "+v"(dv4.y), "+v"(dv4.z), "+v"(dv4.w),
                      "+v"(dm4.x), "+v"(dm4.y), "+v"(dm4.z), "+v"(dm4.w));
    asm volatile("" : "+v"(bb[0]), "+v"(bb[1]), "+v"(bb[2]), "+v"(bb[3]));

    __syncthreads();

    unsigned short* lin = buf;
#pragma unroll
    for (int h = 0; h < 2; ++h) {
#pragma unroll
        for (int ti = 0; ti < 4; ++ti) {
            int cb = w * 64 + ti * 16 + c;
            const f32x4 a = acc[ti * 2 + h];
            unsigned int p01 = cvt_pk_bf16(a[0] + bb[ti], a[1] + bb[ti]);
            unsigned int p23 = cvt_pk_bf16(a[2] + bb[ti], a[3] + bb[ti]);
            int rbase = h * 16 + q * 4;
            lin[(rbase + 0) * LSTRIDE + cb] = (unsigned short)(p01 & 0xffffu);
            lin[(rbase + 1) * LSTRIDE + cb] = (unsigned short)(p01 >> 16);
            lin[(rbase + 2) * LSTRIDE + cb] = (unsigned short)(p23 & 0xffffu);
            lin[(rbase + 3) * LSTRIDE + cb] = (unsigned short)(p23 >> 16);
        }
    }
    __syncthreads();

    float dca[4] = {fmaxf(dv4.x, EPS_), fmaxf(dv4.y, EPS_),
                    fmaxf(dv4.z, EPS_), fmaxf(dv4.w, EPS_)};
    float sqa[4] = {sqrtf(dca[0]), sqrtf(dca[1]), sqrtf(dca[2]), sqrtf(dca[3])};
    float dma[4] = {dm4.x, dm4.y, dm4.z, dm4.w};
    float sldv = __logf(dca[0]) + __logf(dca[1]) + __logf(dca[2]) + __logf(dca[3]);

#pragma unroll
    for (int pp = 0; pp < 4; ++pp) {
        int rl  = pp * 8 + w;
        long bt = (row0 + rl) * Tsz + t;

        short8 l8 = *(const short8*)&lin[rl * LSTRIDE + t * 8];
        float lm[4], lv[4];
#pragma unroll
        for (int d = 0; d < 4; ++d) {
            lm[d] = bf2f((unsigned short)l8[d]);
            lv[d] = bf2f((unsigned short)l8[4 + d]);
        }
        float mk = (float)mp[pp];
        float xa[4] = {xp[pp].x, xp[pp].y, xp[pp].z, xp[pp].w};

        float mean_o[4], var_o[4];
        float s = sldv;
        float evp = 1.f;
#pragma unroll
        for (int d = 0; d < 4; ++d) {
            float mean = fmaf(sqa[d], lm[d], dma[d]);
            float v    = lv[d];
            float sp   = fmaxf(v, 0.f) + __logf(1.f + __expf(-fabsf(v)));
            float ev   = fminf(fmaxf(sp, EPS_), 1e20f);
            float var  = dca[d] * ev;
            float diff = xa[d] - mean;
            s = fmaf(diff * diff, __builtin_amdgcn_rcpf(var), s);
            evp *= ev;
            mean_o[d] = mean;
            var_o[d]  = var;
        }
        s += __logf(evp);
        float logp = -0.5f * (s + 4.f * LOG2PI_);

        float lx = logp * mk;
        out[bt]         = lx;
        out[BTtot + bt] = logp - lx;
        *(float4*)(out + 2L * BTtot + bt * 4) =
            (float4){mean_o[0], mean_o[1], mean_o[2], mean_o[3]};
        *(float4*)(out + 6L * BTtot + bt * 4) =
            (float4){var_o[0], var_o[1], var_o[2], var_o[3]};
    }
}

// ---------------------------------------------------------------------------
extern "C" void kernel_launch(void* const* d_in, const int* in_sizes, int n_in,
                              void* d_out, int out_size, void* d_ws, size_t ws_size,
                              hipStream_t stream) {
    const float* z     = (const float*)d_in[0];
    const float* bx    = (const float*)d_in[1];
    const int*   miss  = (const int*)d_in[2];
    const float* dmean = (const float*)d_in[3];
    const float* dvar  = (const float*)d_in[4];
    const float* Wy    = (const float*)d_in[5];
    const float* by    = (const float*)d_in[6];
    const float* Wm    = (const float*)d_in[7];
    const float* bm    = (const float*)d_in[8];
    const float* Wv    = (const float*)d_in[9];
    const float* bv    = (const float*)d_in[10];
    float* out = (float*)d_out;

    unsigned short* weff = (unsigned short*)d_ws;                    // 256 KiB
    float* beff = (float*)((char*)d_ws + (size_t)Nsz * Zsz * 2);     // + 2 KiB

    hidec_prep<<<Tsz, Zsz, 0, stream>>>(Wy, by, Wm, bm, Wv, bv, weff, beff);

    if (ws_size >= (size_t)LINP_OFF + LINP_BYTES) {
        unsigned short* linp = (unsigned short*)((char*)d_ws + LINP_OFF);
        hidec_gemm<<<Bsz / BM, NT, 0, stream>>>(z, weff, beff, linp);
        hidec_post<<<Bsz / 4 / 4, 256, 0, stream>>>(bx, miss, dmean, dvar, linp, out);
    } else {
        hidec_fused<<<Bsz / BM, NT, 0, stream>>>(z, bx, miss, dmean, dvar,
                                                 weff, beff, out);
    }
}

// Round 8
// 175.678 us; speedup vs baseline: 1.0508x; 1.0508x over previous
//
#include <hip/hip_runtime.h>

// ---------------------------------------------------------------------------
// HIDecoder fused: y=z@Wy^T+by ; lin_{m,v}=einsum(gamma,W{m,v})+b ; gaussian
// log-lik epilogue.  gamma never materialized:
//   Weff[n=t*8+j][k] = sum_y M_j[t][y]*Wy[t*32+y][k],  M_j = Wm(j<4)/Wv(j>=4)
//   beff[n]          = b_j[t,d] + sum_y by[t*32+y]*M_j[t][y]
// => one (32768 x 512 x 256) bf16-MFMA GEMM + elementwise epilogue.
//
// FINAL (R11 = R9 revert). Session findings:
//  - dur = fixed + hbm_bytes/3.65TB/s across all 7 variants; only traffic
//    and exposed epilogue latency ever moved dur.
//  - Traffic minimum reached here: WRITE 82MiB (ideal), FETCH ~38MiB
//    (inputs ~half L3-resident). 124MB total.
//  - Register prefetch of ALL epilogue globals (pinned with asm "+v" before
//    the barrier; needs cap-128 launch_bounds - at cap-64 the compiler sinks
//    the loads, R7) is worth -6.5us.
//  - Occupancy 33->64% (R5/R6): no BW change. Barrier removal (R4): none.
//    2-tile pipeline (R8): register spill catastrophe. Kernel split (R10):
//    epilogue still pins ~2.5TB/s as a pure stream; +67MB round-trip loses.
//  - Harness fills prove HW writes at 6.7TB/s; the ~2.4TB/s plateau is this
//    workload's mixed-stream property, unmoved by 6 structural attacks.
// ---------------------------------------------------------------------------

#define Bsz   32768
#define Tsz   64
#define Dsz   4
#define Ysz   32
#define Zsz   256
#define Nsz   512
#define BTtot (Bsz * Tsz)
#define EPS_  1e-3f
#define LOG2PI_ 1.8378770664093453f

#define BM       32            // batch rows per block
#define NT       512           // threads per block (8 waves)
#define ASTRIDE  264           // ushorts per staged-z row
#define LSTRIDE  524           // ushorts per lin row (512 + pad 12)

typedef __attribute__((ext_vector_type(4))) float  f32x4;
typedef __attribute__((ext_vector_type(8))) short  short8;
typedef __attribute__((ext_vector_type(2))) unsigned int uint2v;

static __device__ __forceinline__ unsigned short f2bf(float f) {
    unsigned int u = __float_as_uint(f);
    return (unsigned short)((u + 0x7fffu + ((u >> 16) & 1u)) >> 16);   // RNE
}
static __device__ __forceinline__ float bf2f(unsigned short h) {
    return __uint_as_float(((unsigned int)h) << 16);
}
// HW RNE pack: low16 = bf16(a), high16 = bf16(b)
static __device__ __forceinline__ unsigned int cvt_pk_bf16(float a, float b) {
    unsigned int r;
    asm("v_cvt_pk_bf16_f32 %0, %1, %2" : "=v"(r) : "v"(a), "v"(b));
    return r;
}

// ---------------------------------------------------------------------------
// Prep: 64 blocks (one per t) x 256 threads (one per k).
// Writes weff in B-fragment order:
//   addr(n,k) = (((tau*8+kk)*4+q)*16+c)*8 + j,  tau=n>>4, c=n&15,
//   kk=k>>5, q=(k>>3)&3, j=k&7
// ---------------------------------------------------------------------------
__global__ __launch_bounds__(256)
void hidec_prep(const float* __restrict__ Wy, const float* __restrict__ by,
                const float* __restrict__ Wm, const float* __restrict__ bm,
                const float* __restrict__ Wv, const float* __restrict__ bv,
                unsigned short* __restrict__ weff, float* __restrict__ beff) {
    __shared__ float Ml[8][Ysz];
    __shared__ float byl[Ysz];
    const int t   = blockIdx.x;          // 0..63
    const int tid = threadIdx.x;
    {
        int j = tid >> 5, y = tid & 31;
        const float* src = (j < 4) ? Wm : Wv;
        Ml[j][y] = src[(t * Dsz + (j & 3)) * Ysz + y];
    }
    if (tid < Ysz) byl[tid] = by[t * Ysz + tid];
    __syncthreads();

    const int k = tid;                   // 0..255
    const int kk = k >> 5, q = (k >> 3) & 3, je = k & 7;
    float wy[Ysz];
#pragma unroll
    for (int y = 0; y < Ysz; ++y)
        wy[y] = Wy[(size_t)(t * Ysz + y) * Zsz + k];
#pragma unroll
    for (int j = 0; j < 8; ++j) {
        float acc = 0.f;
#pragma unroll
        for (int y = 0; y < Ysz; ++y) acc = fmaf(Ml[j][y], wy[y], acc);
        int n   = t * 8 + j;
        int tau = n >> 4, c = n & 15;
        weff[((((tau * 8 + kk) * 4 + q) * 16 + c) * 8) + je] = f2bf(acc);
    }
    if (tid < 8) {
        int d = tid & 3;
        float s = ((tid < 4) ? bm : bv)[t * Dsz + d];
        for (int y = 0; y < Ysz; ++y) s = fmaf(byl[y], Ml[tid][y], s);
        beff[t * 8 + tid] = s;
    }
}

// ---------------------------------------------------------------------------
// Main: 1024 blocks x 512 threads (8 waves). Wave w owns col-tiles w*4..w*4+3
// (cols w*64..w*64+63) for 2 row-tiles of 16 (BM=32).
// ---------------------------------------------------------------------------
__global__ __launch_bounds__(NT, 4)
void hidec_main(const float* __restrict__ z, const float* __restrict__ bx,
                const int* __restrict__ miss, const float* __restrict__ dmean,
                const float* __restrict__ dvarp, const unsigned short* __restrict__ weff,
                const float* __restrict__ beff, float* __restrict__ out) {
    // a_lds (32 x 264) aliased by lin (32 x 524) after the GEMM
    __shared__ unsigned short buf[BM * LSTRIDE];         // 33536 B

    const int tid  = threadIdx.x;
    const long row0 = (long)blockIdx.x * BM;

    // ---- stage z (32 x 256 fp32) -> bf16 LDS ------------------------------
    unsigned short* a_lds = buf;
#pragma unroll
    for (int i = 0; i < 4; ++i) {
        int idx4 = tid + i * NT;         // 2048 float4-groups
        int r  = idx4 >> 6;
        int c4 = idx4 & 63;
        float4 v = *(const float4*)(z + (row0 + r) * Zsz + c4 * 4);
        uint2v pk;
        pk.x = cvt_pk_bf16(v.x, v.y);
        pk.y = cvt_pk_bf16(v.z, v.w);
        *(uint2v*)&a_lds[r * ASTRIDE + c4 * 4] = pk;
    }
    __syncthreads();

    // ---- GEMM: 32 x 512 x K=256, bf16 MFMA 16x16x32 -----------------------
    const int lane = tid & 63;
    const int w    = tid >> 6;           // wave 0..7
    const int c    = lane & 15;
    const int q    = lane >> 4;

    f32x4 acc[8];                        // [ti*2 + h]
#pragma unroll
    for (int i = 0; i < 8; ++i) acc[i] = (f32x4){0.f, 0.f, 0.f, 0.f};

    // b-fragment base: tau0 = w*4 ; per-(tau,kk) block = 512 ushorts
    const unsigned short* wp = weff + ((size_t)(w * 4) * 8) * 512 + lane * 8;

#pragma unroll
    for (int kk = 0; kk < 8; ++kk) {
        short8 b0 = *(const short8*)(wp + kk * 512 + 0 * 4096);
        short8 b1 = *(const short8*)(wp + kk * 512 + 1 * 4096);
        short8 b2 = *(const short8*)(wp + kk * 512 + 2 * 4096);
        short8 b3 = *(const short8*)(wp + kk * 512 + 3 * 4096);
        short8 a0 = *(const short8*)&a_lds[(0 * 16 + c) * ASTRIDE + kk * 32 + q * 8];
        short8 a1 = *(const short8*)&a_lds[(1 * 16 + c) * ASTRIDE + kk * 32 + q * 8];
        acc[0] = __builtin_amdgcn_mfma_f32_16x16x32_bf16(a0, b0, acc[0], 0, 0, 0);
        acc[1] = __builtin_amdgcn_mfma_f32_16x16x32_bf16(a1, b0, acc[1], 0, 0, 0);
        acc[2] = __builtin_amdgcn_mfma_f32_16x16x32_bf16(a0, b1, acc[2], 0, 0, 0);
        acc[3] = __builtin_amdgcn_mfma_f32_16x16x32_bf16(a1, b1, acc[3], 0, 0, 0);
        acc[4] = __builtin_amdgcn_mfma_f32_16x16x32_bf16(a0, b2, acc[4], 0, 0, 0);
        acc[5] = __builtin_amdgcn_mfma_f32_16x16x32_bf16(a1, b2, acc[5], 0, 0, 0);
        acc[6] = __builtin_amdgcn_mfma_f32_16x16x32_bf16(a0, b3, acc[6], 0, 0, 0);
        acc[7] = __builtin_amdgcn_mfma_f32_16x16x32_bf16(a1, b3, acc[7], 0, 0, 0);
    }

    // ---- PREFETCH all epilogue globals (issue now; cap-128 gives slack) ---
    const int t = lane;                  // fixed per thread for postprocess
    float4 dv4 = *(const float4*)(dvarp + t * 4);
    float4 dm4 = *(const float4*)(dmean + t * 4);
    float4 xp[4];
    int    mp[4];
#pragma unroll
    for (int pp = 0; pp < 4; ++pp) {
        long bt = (row0 + pp * 8 + w) * Tsz + t;
        xp[pp] = *(const float4*)(bx + bt * 4);
        mp[pp] = miss[bt];
    }
    float bb[4];
#pragma unroll
    for (int ti = 0; ti < 4; ++ti) bb[ti] = beff[w * 64 + ti * 16 + c];

    // Pin the prefetched values into registers HERE so the loads cannot be
    // sunk past the barrier (R7 failure mode). The barrier's own vmcnt(0)
    // drain completes them with all waves' loads overlapping.
#pragma unroll
    for (int pp = 0; pp < 4; ++pp) {
        asm volatile("" : "+v"(xp[pp].x), "+v"(xp[pp].y),
                          "+v"(xp[pp].z), "+v"(xp[pp].w), "+v"(mp[pp]));
    }
    asm volatile("" : "+v"(dv4.x), "+v"(dv4.y), "+v"(dv4.z), "+v"(dv4.w),
                      "+v"(dm4.x), "+v"(dm4.y), "+v"(dm4.z), "+v"(dm4.w));
    asm volatile("" : "+v"(bb[0]), "+v"(bb[1]), "+v"(bb[2]), "+v"(bb[3]));

    __syncthreads();                     // all waves done reading a_lds

    // ---- write lin (bf16) into LDS, block-wide ----------------------------
    unsigned short* lin = buf;           // aliases a_lds
#pragma unroll
    for (int h = 0; h < 2; ++h) {
#pragma unroll
        for (int ti = 0; ti < 4; ++ti) {
            int cb = w * 64 + ti * 16 + c;   // global col 0..511
            const f32x4 a = acc[ti * 2 + h];
            unsigned int p01 = cvt_pk_bf16(a[0] + bb[ti], a[1] + bb[ti]);
            unsigned int p23 = cvt_pk_bf16(a[2] + bb[ti], a[3] + bb[ti]);
            int rbase = h * 16 + q * 4;
            lin[(rbase + 0) * LSTRIDE + cb] = (unsigned short)(p01 & 0xffffu);
            lin[(rbase + 1) * LSTRIDE + cb] = (unsigned short)(p01 >> 16);
            lin[(rbase + 2) * LSTRIDE + cb] = (unsigned short)(p23 & 0xffffu);
            lin[(rbase + 3) * LSTRIDE + cb] = (unsigned short)(p23 >> 16);
        }
    }
    __syncthreads();

    // ---- postprocess: thread serves t = lane, rows pp*8 + w ---------------
    // everything below runs out of registers + LDS; zero global loads
    float dca[4] = {fmaxf(dv4.x, EPS_), fmaxf(dv4.y, EPS_),
                    fmaxf(dv4.z, EPS_), fmaxf(dv4.w, EPS_)};
    float sqa[4] = {sqrtf(dca[0]), sqrtf(dca[1]), sqrtf(dca[2]), sqrtf(dca[3])};
    float dma[4] = {dm4.x, dm4.y, dm4.z, dm4.w};
    float sldv = __logf(dca[0]) + __logf(dca[1]) + __logf(dca[2]) + __logf(dca[3]);

#pragma unroll
    for (int pp = 0; pp < 4; ++pp) {
        int rl  = pp * 8 + w;            // 0..31
        long bt = (row0 + rl) * Tsz + t;

        short8 l8 = *(const short8*)&lin[rl * LSTRIDE + t * 8];
        float lm[4], lv[4];
#pragma unroll
        for (int d = 0; d < 4; ++d) {
            lm[d] = bf2f((unsigned short)l8[d]);
            lv[d] = bf2f((unsigned short)l8[4 + d]);
        }

        float mk = (float)mp[pp];
        float xa[4] = {xp[pp].x, xp[pp].y, xp[pp].z, xp[pp].w};

        float mean_o[4], var_o[4];
        float s = sldv;
        float evp = 1.f;
#pragma unroll
        for (int d = 0; d < 4; ++d) {
            float mean = fmaf(sqa[d], lm[d], dma[d]);
            float v    = lv[d];
            float sp   = fmaxf(v, 0.f) + __logf(1.f + __expf(-fabsf(v)));
            float ev   = fminf(fmaxf(sp, EPS_), 1e20f);
            float var  = dca[d] * ev;
            float diff = xa[d] - mean;
            s = fmaf(diff * diff, __builtin_amdgcn_rcpf(var), s);
            evp *= ev;
            mean_o[d] = mean;
            var_o[d]  = var;
        }
        s += __logf(evp);
        float logp = -0.5f * (s + 4.f * LOG2PI_);

        float lx = logp * mk;
        out[bt]         = lx;              // log_p_x      (256B/wave contig)
        out[BTtot + bt] = logp - lx;       // log_p_x_missing

        *(float4*)(out + 2L * BTtot + bt * 4) =
            (float4){mean_o[0], mean_o[1], mean_o[2], mean_o[3]};
        *(float4*)(out + 6L * BTtot + bt * 4) =
            (float4){var_o[0], var_o[1], var_o[2], var_o[3]};
    }
}

// ---------------------------------------------------------------------------
extern "C" void kernel_launch(void* const* d_in, const int* in_sizes, int n_in,
                              void* d_out, int out_size, void* d_ws, size_t ws_size,
                              hipStream_t stream) {
    const float* z     = (const float*)d_in[0];
    const float* bx    = (const float*)d_in[1];
    const int*   miss  = (const int*)d_in[2];
    const float* dmean = (const float*)d_in[3];
    const float* dvar  = (const float*)d_in[4];
    const float* Wy    = (const float*)d_in[5];
    const float* by    = (const float*)d_in[6];
    const float* Wm    = (const float*)d_in[7];
    const float* bm    = (const float*)d_in[8];
    const float* Wv    = (const float*)d_in[9];
    const float* bv    = (const float*)d_in[10];
    float* out = (float*)d_out;

    unsigned short* weff = (unsigned short*)d_ws;                    // 256 KiB
    float* beff = (float*)((char*)d_ws + (size_t)Nsz * Zsz * 2);     // + 2 KiB

    hidec_prep<<<Tsz, Zsz, 0, stream>>>(Wy, by, Wm, bm, Wv, bv, weff, beff);
    hidec_main<<<Bsz / BM, NT, 0, stream>>>(z, bx, miss, dmean, dvar, weff, beff, out);
}